// Round 2
// baseline (479.668 us; speedup 1.0000x reference)
//
#include <hip/hip_runtime.h>
#include <math.h>

#define V_ 128
#define K_ 32
#define C_ 256
#define L_ 4
#define N_ 4096
#define F_ 16
#define E_ 8192
#define B_ 512
#define EPS_ 1e-6f

// ---------------------------------------------------------------------------
// Kernel 1: normalize sum_params in log domain.
// lw_sum[l,n,f] = log(sp+EPS) - log(sum_f(sp+EPS)).  One thread per (l,n) row.
// ---------------------------------------------------------------------------
__global__ __launch_bounds__(256) void norm_sum_kernel(const float* __restrict__ sp,
                                                       float* __restrict__ lws) {
    int idx = blockIdx.x * 256 + threadIdx.x;   // (l,n) row id, L*N = 16384
    if (idx >= L_ * N_) return;
    const float* row = sp + (size_t)idx * F_;
    float v[F_];
    float s = 0.f;
#pragma unroll
    for (int f = 0; f < F_; f++) { v[f] = row[f] + EPS_; s += v[f]; }
    float ls = __logf(s);
#pragma unroll
    for (int f = 0; f < F_; f++) lws[(size_t)idx * F_ + f] = __logf(v[f]) - ls;
}

// ---------------------------------------------------------------------------
// Kernel 2: input layer.  One block per n = v*K + k (4096 blocks, 256 thr).
// Phase 1: block-reduce sum over C=256 of (ip+EPS).
// Phase 2: nm0[n*B+b] = log(ip[n*C + inputs[b,v]] + EPS) - log(sum).
// ---------------------------------------------------------------------------
__global__ __launch_bounds__(256) void input_kernel(const float* __restrict__ ip,
                                                    const int* __restrict__ inputs,
                                                    float* __restrict__ nm0) {
    int n   = blockIdx.x;          // v*K + k
    int v   = n >> 5;              // K = 32
    int tid = threadIdx.x;
    const float* row = ip + (size_t)n * C_;

    // block sum over C (blockDim == C == 256)
    float t = row[tid] + EPS_;
    __shared__ float smem[4];
#pragma unroll
    for (int off = 32; off; off >>= 1) t += __shfl_down(t, off, 64);
    if ((tid & 63) == 0) smem[tid >> 6] = t;
    __syncthreads();
    float ls = __logf(smem[0] + smem[1] + smem[2] + smem[3]);

#pragma unroll
    for (int bi = 0; bi < 2; bi++) {
        int b  = bi * 256 + tid;
        int xv = inputs[b * V_ + v];               // category in [0, C)
        nm0[(size_t)n * B_ + b] = __logf(row[xv] + EPS_) - ls;
    }
}

// ---------------------------------------------------------------------------
// Kernel 3: one circuit layer, em fused (never materialized).
// nm_out[n,b] = logsumexp_f( nm_in[c0,b] + nm_in[c1,b] + lw_sum[l,n,f] )
// Block = n (4096 blocks), 256 threads; each thread owns b and b+256.
// Indices/weights are block-uniform -> staged in LDS.
// ---------------------------------------------------------------------------
__global__ __launch_bounds__(256) void layer_kernel(const float* __restrict__ nm_in,
                                                    float* __restrict__ nm_out,
                                                    const int* __restrict__ prod,
                                                    const int* __restrict__ sc,
                                                    const float* __restrict__ lws,
                                                    int l) {
    int n   = blockIdx.x;
    int tid = threadIdx.x;
    __shared__ int   s_c0[F_];
    __shared__ int   s_c1[F_];
    __shared__ float s_lw[F_];
    if (tid < F_) {
        int e = sc[((size_t)l * N_ + n) * F_ + tid];
        s_c0[tid] = prod[((size_t)l * E_ + e) * 2 + 0];
        s_c1[tid] = prod[((size_t)l * E_ + e) * 2 + 1];
        s_lw[tid] = lws[((size_t)l * N_ + n) * F_ + tid];
    }
    __syncthreads();

    int b0 = tid, b1 = tid + 256;
    float a0[F_], a1[F_];
#pragma unroll
    for (int f = 0; f < F_; f++) {
        int   c0 = s_c0[f], c1 = s_c1[f];
        float w  = s_lw[f];
        a0[f] = nm_in[(size_t)c0 * B_ + b0] + nm_in[(size_t)c1 * B_ + b0] + w;
        a1[f] = nm_in[(size_t)c0 * B_ + b1] + nm_in[(size_t)c1 * B_ + b1] + w;
    }
    float m0 = a0[0], m1 = a1[0];
#pragma unroll
    for (int f = 1; f < F_; f++) { m0 = fmaxf(m0, a0[f]); m1 = fmaxf(m1, a1[f]); }
    float s0 = 0.f, s1 = 0.f;
#pragma unroll
    for (int f = 0; f < F_; f++) { s0 += __expf(a0[f] - m0); s1 += __expf(a1[f] - m1); }
    nm_out[(size_t)n * B_ + b0] = m0 + __logf(s0);
    nm_out[(size_t)n * B_ + b1] = m1 + __logf(s1);
}

// ---------------------------------------------------------------------------
// Kernel 4: root.  out[b] = logsumexp_n(nm[n,b] + log(rp[n]+EPS)) - log(sum(rp+EPS))
// Grid = 8 blocks x 256 threads; each block owns 64 consecutive b (one/lane),
// 4 waves stripe the n dimension, then cross-wave logsumexp merge via LDS.
// ---------------------------------------------------------------------------
__global__ __launch_bounds__(256) void root_kernel(const float* __restrict__ nm,
                                                   const float* __restrict__ rp,
                                                   float* __restrict__ out) {
    int tid  = threadIdx.x;
    int lane = tid & 63;
    int w    = tid >> 6;
    int b    = blockIdx.x * 64 + lane;

    // lroot = log(sum_n (rp+EPS)), block-redundant reduction
    __shared__ float smem[4];
    float acc = 0.f;
    for (int i = tid; i < N_; i += 256) acc += rp[i] + EPS_;
#pragma unroll
    for (int off = 32; off; off >>= 1) acc += __shfl_down(acc, off, 64);
    if (lane == 0) smem[w] = acc;
    __syncthreads();
    float lroot = __logf(smem[0] + smem[1] + smem[2] + smem[3]);

    // online logsumexp over this wave's n-stripe
    float m = -INFINITY, s = 0.f;
    for (int n = w; n < N_; n += 4) {
        float a    = nm[(size_t)n * B_ + b] + __logf(rp[n] + EPS_);
        float mnew = fmaxf(m, a);
        s = s * __expf(m - mnew) + __expf(a - mnew);
        m = mnew;
    }

    // merge the 4 wave partials per b
    __shared__ float sm[4][64];
    __shared__ float ss[4][64];
    sm[w][lane] = m;
    ss[w][lane] = s;
    __syncthreads();
    if (w == 0) {
        float M = sm[0][lane], S = ss[0][lane];
#pragma unroll
        for (int i = 1; i < 4; i++) {
            float m2 = sm[i][lane], s2 = ss[i][lane];
            float Mn = fmaxf(M, m2);
            S = S * __expf(M - Mn) + s2 * __expf(m2 - Mn);
            M = Mn;
        }
        out[b] = M + __logf(S) - lroot;
    }
}

extern "C" void kernel_launch(void* const* d_in, const int* in_sizes, int n_in,
                              void* d_out, int out_size, void* d_ws, size_t ws_size,
                              hipStream_t stream) {
    const int*   inputs = (const int*)d_in[0];     // (B, V) int32
    const int*   prod   = (const int*)d_in[1];     // (L, E, 2) int32
    const int*   sc     = (const int*)d_in[2];     // (L, N, F) int32
    const float* ip     = (const float*)d_in[3];   // (V, K, C) f32
    const float* sp     = (const float*)d_in[4];   // (L, N, F) f32
    const float* rp     = (const float*)d_in[5];   // (N,) f32
    float* out = (float*)d_out;                    // (B,) f32

    float* nm0 = (float*)d_ws;                     // N*B floats (8 MB)
    float* nm1 = nm0 + (size_t)N_ * B_;            // N*B floats (8 MB)
    float* lws = nm1 + (size_t)N_ * B_;            // L*N*F floats (1 MB)

    norm_sum_kernel<<<(L_ * N_ + 255) / 256, 256, 0, stream>>>(sp, lws);
    input_kernel<<<N_, 256, 0, stream>>>(ip, inputs, nm0);

    float* bufs[2] = {nm0, nm1};
    for (int l = 0; l < L_; l++)
        layer_kernel<<<N_, 256, 0, stream>>>(bufs[l & 1], bufs[(l + 1) & 1],
                                             prod, sc, lws, l);
    // after L=4 layers the live buffer is bufs[0] = nm0
    root_kernel<<<B_ / 64, 256, 0, stream>>>(bufs[L_ & 1], rp, out);
}

// Round 3
// 187.426 us; speedup vs baseline: 2.5592x; 2.5592x over previous
//
#include <hip/hip_runtime.h>
#include <math.h>

#define V_ 128
#define K_ 32
#define C_ 256
#define L_ 4
#define N_ 4096
#define F_ 16
#define E_ 8192
#define B_ 512
#define EPS_ 1e-6f

#define RCHUNKS 32            // n-chunks for root phase A
#define CHUNK_N (N_ / RCHUNKS)  // 128

// ---------------------------------------------------------------------------
// Kernel 1: normalize sum_params in log domain.
// lw_sum[l,n,f] = log(sp+EPS) - log(sum_f(sp+EPS)).  One thread per (l,n) row.
// ---------------------------------------------------------------------------
__global__ __launch_bounds__(256) void norm_sum_kernel(const float* __restrict__ sp,
                                                       float* __restrict__ lws) {
    int idx = blockIdx.x * 256 + threadIdx.x;   // (l,n) row id, L*N = 16384
    if (idx >= L_ * N_) return;
    const float* row = sp + (size_t)idx * F_;
    float v[F_];
    float s = 0.f;
#pragma unroll
    for (int f = 0; f < F_; f++) { v[f] = row[f] + EPS_; s += v[f]; }
    float ls = __logf(s);
#pragma unroll
    for (int f = 0; f < F_; f++) lws[(size_t)idx * F_ + f] = __logf(v[f]) - ls;
}

// ---------------------------------------------------------------------------
// Kernel 2: input layer.  One block per n = v*K + k (4096 blocks, 256 thr).
// ---------------------------------------------------------------------------
__global__ __launch_bounds__(256) void input_kernel(const float* __restrict__ ip,
                                                    const int* __restrict__ inputs,
                                                    float* __restrict__ nm0) {
    int n   = blockIdx.x;          // v*K + k
    int v   = n >> 5;              // K = 32
    int tid = threadIdx.x;
    const float* row = ip + (size_t)n * C_;

    float t = row[tid] + EPS_;
    __shared__ float smem[4];
#pragma unroll
    for (int off = 32; off; off >>= 1) t += __shfl_down(t, off, 64);
    if ((tid & 63) == 0) smem[tid >> 6] = t;
    __syncthreads();
    float ls = __logf(smem[0] + smem[1] + smem[2] + smem[3]);

#pragma unroll
    for (int bi = 0; bi < 2; bi++) {
        int b  = bi * 256 + tid;
        int xv = inputs[b * V_ + v];               // category in [0, C)
        nm0[(size_t)n * B_ + b] = __logf(row[xv] + EPS_) - ls;
    }
}

// ---------------------------------------------------------------------------
// Kernel 3: one circuit layer, em fused (never materialized).
// nm_out[n,b] = logsumexp_f( nm_in[c0,b] + nm_in[c1,b] + lw_sum[l,n,f] )
// ---------------------------------------------------------------------------
__global__ __launch_bounds__(256) void layer_kernel(const float* __restrict__ nm_in,
                                                    float* __restrict__ nm_out,
                                                    const int* __restrict__ prod,
                                                    const int* __restrict__ sc,
                                                    const float* __restrict__ lws,
                                                    int l) {
    int n   = blockIdx.x;
    int tid = threadIdx.x;
    __shared__ int   s_c0[F_];
    __shared__ int   s_c1[F_];
    __shared__ float s_lw[F_];
    if (tid < F_) {
        int e = sc[((size_t)l * N_ + n) * F_ + tid];
        s_c0[tid] = prod[((size_t)l * E_ + e) * 2 + 0];
        s_c1[tid] = prod[((size_t)l * E_ + e) * 2 + 1];
        s_lw[tid] = lws[((size_t)l * N_ + n) * F_ + tid];
    }
    __syncthreads();

    int b0 = tid, b1 = tid + 256;
    float a0[F_], a1[F_];
#pragma unroll
    for (int f = 0; f < F_; f++) {
        int   c0 = s_c0[f], c1 = s_c1[f];
        float w  = s_lw[f];
        a0[f] = nm_in[(size_t)c0 * B_ + b0] + nm_in[(size_t)c1 * B_ + b0] + w;
        a1[f] = nm_in[(size_t)c0 * B_ + b1] + nm_in[(size_t)c1 * B_ + b1] + w;
    }
    float m0 = a0[0], m1 = a1[0];
#pragma unroll
    for (int f = 1; f < F_; f++) { m0 = fmaxf(m0, a0[f]); m1 = fmaxf(m1, a1[f]); }
    float s0 = 0.f, s1 = 0.f;
#pragma unroll
    for (int f = 0; f < F_; f++) { s0 += __expf(a0[f] - m0); s1 += __expf(a1[f] - m1); }
    nm_out[(size_t)n * B_ + b0] = m0 + __logf(s0);
    nm_out[(size_t)n * B_ + b1] = m1 + __logf(s1);
}

// ---------------------------------------------------------------------------
// Kernel 4a: root phase A — partial logsumexp over an n-chunk.
// Grid = RCHUNKS x 8 b-groups = 256 blocks, 256 threads (4 waves).
// Wave w strides n within the chunk; lanes cover 64 consecutive b (coalesced).
// Per-(chunk,b) partial (m, s) written to workspace.
// ---------------------------------------------------------------------------
__global__ __launch_bounds__(256) void root_partial_kernel(const float* __restrict__ nm,
                                                           const float* __restrict__ rp,
                                                           float* __restrict__ pm,
                                                           float* __restrict__ ps) {
    int chunk = blockIdx.x >> 3;          // 0..31
    int bg    = blockIdx.x & 7;           // 0..7
    int tid   = threadIdx.x;
    int lane  = tid & 63;
    int w     = tid >> 6;                 // 0..3
    int b     = bg * 64 + lane;
    int n0    = chunk * CHUNK_N;

    float m = -INFINITY, s = 0.f;
    for (int i = w; i < CHUNK_N; i += 4) {
        int   n    = n0 + i;
        float a    = nm[(size_t)n * B_ + b] + __logf(rp[n] + EPS_);
        float mnew = fmaxf(m, a);
        s = s * __expf(m - mnew) + __expf(a - mnew);
        m = mnew;
    }

    // merge the 4 wave partials per b within the block
    __shared__ float sm[4][64];
    __shared__ float ss[4][64];
    sm[w][lane] = m;
    ss[w][lane] = s;
    __syncthreads();
    if (w == 0) {
        float M = sm[0][lane], S = ss[0][lane];
#pragma unroll
        for (int i = 1; i < 4; i++) {
            float m2 = sm[i][lane], s2 = ss[i][lane];
            float Mn = fmaxf(M, m2);
            S = S * __expf(M - Mn) + s2 * __expf(m2 - Mn);
            M = Mn;
        }
        pm[chunk * B_ + b] = M;
        ps[chunk * B_ + b] = S;
    }
}

// ---------------------------------------------------------------------------
// Kernel 4b: root phase B — merge RCHUNKS partials per b, subtract lroot.
// Grid = 2 blocks x 256 threads, one thread per b.
// ---------------------------------------------------------------------------
__global__ __launch_bounds__(256) void root_merge_kernel(const float* __restrict__ pm,
                                                         const float* __restrict__ ps,
                                                         const float* __restrict__ rp,
                                                         float* __restrict__ out) {
    int tid = threadIdx.x;
    int b   = blockIdx.x * 256 + tid;

    // lroot = log(sum_n (rp+EPS)), block-redundant reduction
    __shared__ float smem[4];
    float acc = 0.f;
    for (int i = tid; i < N_; i += 256) acc += rp[i] + EPS_;
#pragma unroll
    for (int off = 32; off; off >>= 1) acc += __shfl_down(acc, off, 64);
    if ((tid & 63) == 0) smem[tid >> 6] = acc;
    __syncthreads();
    float lroot = __logf(smem[0] + smem[1] + smem[2] + smem[3]);

    float M = -INFINITY, S = 0.f;
#pragma unroll
    for (int c = 0; c < RCHUNKS; c++) {
        float m2 = pm[c * B_ + b], s2 = ps[c * B_ + b];
        float Mn = fmaxf(M, m2);
        S = S * __expf(M - Mn) + s2 * __expf(m2 - Mn);
        M = Mn;
    }
    out[b] = M + __logf(S) - lroot;
}

extern "C" void kernel_launch(void* const* d_in, const int* in_sizes, int n_in,
                              void* d_out, int out_size, void* d_ws, size_t ws_size,
                              hipStream_t stream) {
    const int*   inputs = (const int*)d_in[0];     // (B, V) int32
    const int*   prod   = (const int*)d_in[1];     // (L, E, 2) int32
    const int*   sc     = (const int*)d_in[2];     // (L, N, F) int32
    const float* ip     = (const float*)d_in[3];   // (V, K, C) f32
    const float* sp     = (const float*)d_in[4];   // (L, N, F) f32
    const float* rp     = (const float*)d_in[5];   // (N,) f32
    float* out = (float*)d_out;                    // (B,) f32

    float* nm0 = (float*)d_ws;                     // N*B floats (8 MB)
    float* nm1 = nm0 + (size_t)N_ * B_;            // N*B floats (8 MB)
    float* lws = nm1 + (size_t)N_ * B_;            // L*N*F floats (1 MB)
    float* pm  = lws + (size_t)L_ * N_ * F_;       // RCHUNKS*B floats (64 KB)
    float* ps  = pm + (size_t)RCHUNKS * B_;        // RCHUNKS*B floats (64 KB)

    norm_sum_kernel<<<(L_ * N_ + 255) / 256, 256, 0, stream>>>(sp, lws);
    input_kernel<<<N_, 256, 0, stream>>>(ip, inputs, nm0);

    float* bufs[2] = {nm0, nm1};
    for (int l = 0; l < L_; l++)
        layer_kernel<<<N_, 256, 0, stream>>>(bufs[l & 1], bufs[(l + 1) & 1],
                                             prod, sc, lws, l);
    // after L=4 layers the live buffer is bufs[0] = nm0
    root_partial_kernel<<<RCHUNKS * 8, 256, 0, stream>>>(bufs[L_ & 1], rp, pm, ps);
    root_merge_kernel<<<B_ / 256, 256, 0, stream>>>(pm, ps, rp, out);
}

// Round 4
// 154.397 us; speedup vs baseline: 3.1067x; 1.2139x over previous
//
#include <hip/hip_runtime.h>
#include <math.h>

#define V_ 128
#define K_ 32
#define C_ 256
#define L_ 4
#define N_ 4096
#define F_ 16
#define E_ 8192
#define B_ 512
#define EPS_ 1e-6f

#define RCHUNKS 32              // n-chunks for root phase A
#define CHUNK_N (N_ / RCHUNKS)  // 128

// ---------------------------------------------------------------------------
// Kernel 1: normalize sum_params in log domain.
// lw_sum[l,n,f] = log(sp+EPS) - log(sum_f(sp+EPS)).  One thread per (l,n) row.
// ---------------------------------------------------------------------------
__global__ __launch_bounds__(256) void norm_sum_kernel(const float* __restrict__ sp,
                                                       float* __restrict__ lws) {
    int idx = blockIdx.x * 256 + threadIdx.x;   // (l,n) row id, L*N = 16384
    if (idx >= L_ * N_) return;
    const float* row = sp + (size_t)idx * F_;
    float v[F_];
    float s = 0.f;
#pragma unroll
    for (int f = 0; f < F_; f++) { v[f] = row[f] + EPS_; s += v[f]; }
    float ls = __logf(s);
#pragma unroll
    for (int f = 0; f < F_; f++) lws[(size_t)idx * F_ + f] = __logf(v[f]) - ls;
}

// ---------------------------------------------------------------------------
// Kernel 2a: per-row input normalizer.  ls[n] = log(sum_c(ip[n,:]+EPS)).
// One wave per row; grid = N/4 blocks x 256 threads.
// ---------------------------------------------------------------------------
__global__ __launch_bounds__(256) void row_ls_kernel(const float* __restrict__ ip,
                                                     float* __restrict__ ls) {
    int n    = blockIdx.x * 4 + (threadIdx.x >> 6);
    int lane = threadIdx.x & 63;
    const float* row = ip + (size_t)n * C_;
    float t = 0.f;
#pragma unroll
    for (int i = 0; i < 4; i++) t += row[lane + 64 * i] + EPS_;
#pragma unroll
    for (int off = 32; off; off >>= 1) t += __shfl_down(t, off, 64);
    if (lane == 0) ls[n] = __logf(t);
}

// ---------------------------------------------------------------------------
// Kernel 2b: input layer gather, XCD b-partitioned.
// bg = blockIdx%8 selects a 64-wide b-slice -> round-robin maps it to one XCD,
// so the nm0 slice this XCD writes is the slice it will read in layer 0.
// Grid = 8 * (N/4) blocks, 256 threads; wave w handles n = ng*4+w.
// ---------------------------------------------------------------------------
__global__ __launch_bounds__(256) void input_kernel(const float* __restrict__ ip,
                                                    const int* __restrict__ inputs,
                                                    const float* __restrict__ ls,
                                                    float* __restrict__ nm0) {
    int blk  = blockIdx.x;
    int bg   = blk & 7;
    int ng   = blk >> 3;
    int w    = threadIdx.x >> 6;
    int lane = threadIdx.x & 63;
    int n    = ng * 4 + w;
    int v    = n >> 5;               // K = 32
    int b    = bg * 64 + lane;
    int xv   = inputs[b * V_ + v];   // category in [0, C)
    nm0[(size_t)n * B_ + b] = __logf(ip[(size_t)n * C_ + xv] + EPS_) - ls[n];
}

// ---------------------------------------------------------------------------
// Kernel 3: one circuit layer, em fused, XCD b-partitioned.
// nm_out[n,b] = logsumexp_f( nm_in[c0,b] + nm_in[c1,b] + lw_sum[l,n,f] )
// bg = blockIdx%8 -> XCD k only touches nm[:, 64k:64k+64] = 1 MB (L2-resident).
// Grid = 8 * (N/4) blocks, 256 threads (4 waves = 4 n's, same b-slice).
// ---------------------------------------------------------------------------
__global__ __launch_bounds__(256) void layer_kernel(const float* __restrict__ nm_in,
                                                    float* __restrict__ nm_out,
                                                    const int* __restrict__ prod,
                                                    const int* __restrict__ sc,
                                                    const float* __restrict__ lws,
                                                    int l) {
    int blk  = blockIdx.x;
    int bg   = blk & 7;           // b-slice / XCD (low bits -> round-robin)
    int ng   = blk >> 3;          // n-group of 4
    int tid  = threadIdx.x;
    int w    = tid >> 6;
    int lane = tid & 63;
    int n    = ng * 4 + w;
    int b    = bg * 64 + lane;

    __shared__ int   s_c0[4][F_];
    __shared__ int   s_c1[4][F_];
    __shared__ float s_lw[4][F_];
    if (tid < 64) {
        int w2 = tid >> 4, f = tid & 15;
        int n2 = ng * 4 + w2;
        int e  = sc[((size_t)l * N_ + n2) * F_ + f];
        s_c0[w2][f] = prod[((size_t)l * E_ + e) * 2 + 0];
        s_c1[w2][f] = prod[((size_t)l * E_ + e) * 2 + 1];
        s_lw[w2][f] = lws[((size_t)l * N_ + n2) * F_ + f];
    }
    __syncthreads();

    float a[F_];
#pragma unroll
    for (int f = 0; f < F_; f++) {
        a[f] = nm_in[(size_t)s_c0[w][f] * B_ + b]
             + nm_in[(size_t)s_c1[w][f] * B_ + b]
             + s_lw[w][f];
    }
    float m = a[0];
#pragma unroll
    for (int f = 1; f < F_; f++) m = fmaxf(m, a[f]);
    float s = 0.f;
#pragma unroll
    for (int f = 0; f < F_; f++) s += __expf(a[f] - m);
    nm_out[(size_t)n * B_ + b] = m + __logf(s);
}

// ---------------------------------------------------------------------------
// Kernel 4a: root phase A — partial logsumexp over an n-chunk.
// Grid = RCHUNKS x 8 b-groups (bg in LOW bits -> same XCD slice as layers).
// ---------------------------------------------------------------------------
__global__ __launch_bounds__(256) void root_partial_kernel(const float* __restrict__ nm,
                                                           const float* __restrict__ rp,
                                                           float* __restrict__ pm,
                                                           float* __restrict__ ps) {
    int bg    = blockIdx.x & 7;           // 0..7 (XCD slice)
    int chunk = blockIdx.x >> 3;          // 0..31
    int tid   = threadIdx.x;
    int lane  = tid & 63;
    int w     = tid >> 6;                 // 0..3
    int b     = bg * 64 + lane;
    int n0    = chunk * CHUNK_N;

    float m = -INFINITY, s = 0.f;
    for (int i = w; i < CHUNK_N; i += 4) {
        int   n    = n0 + i;
        float a    = nm[(size_t)n * B_ + b] + __logf(rp[n] + EPS_);
        float mnew = fmaxf(m, a);
        s = s * __expf(m - mnew) + __expf(a - mnew);
        m = mnew;
    }

    __shared__ float sm[4][64];
    __shared__ float ss[4][64];
    sm[w][lane] = m;
    ss[w][lane] = s;
    __syncthreads();
    if (w == 0) {
        float M = sm[0][lane], S = ss[0][lane];
#pragma unroll
        for (int i = 1; i < 4; i++) {
            float m2 = sm[i][lane], s2 = ss[i][lane];
            float Mn = fmaxf(M, m2);
            S = S * __expf(M - Mn) + s2 * __expf(m2 - Mn);
            M = Mn;
        }
        pm[chunk * B_ + b] = M;
        ps[chunk * B_ + b] = S;
    }
}

// ---------------------------------------------------------------------------
// Kernel 4b: root phase B — merge RCHUNKS partials per b, subtract lroot.
// ---------------------------------------------------------------------------
__global__ __launch_bounds__(256) void root_merge_kernel(const float* __restrict__ pm,
                                                         const float* __restrict__ ps,
                                                         const float* __restrict__ rp,
                                                         float* __restrict__ out) {
    int tid = threadIdx.x;
    int b   = blockIdx.x * 256 + tid;

    __shared__ float smem[4];
    float acc = 0.f;
    for (int i = tid; i < N_; i += 256) acc += rp[i] + EPS_;
#pragma unroll
    for (int off = 32; off; off >>= 1) acc += __shfl_down(acc, off, 64);
    if ((tid & 63) == 0) smem[tid >> 6] = acc;
    __syncthreads();
    float lroot = __logf(smem[0] + smem[1] + smem[2] + smem[3]);

    float M = -INFINITY, S = 0.f;
#pragma unroll
    for (int c = 0; c < RCHUNKS; c++) {
        float m2 = pm[c * B_ + b], s2 = ps[c * B_ + b];
        float Mn = fmaxf(M, m2);
        S = S * __expf(M - Mn) + s2 * __expf(m2 - Mn);
        M = Mn;
    }
    out[b] = M + __logf(S) - lroot;
}

extern "C" void kernel_launch(void* const* d_in, const int* in_sizes, int n_in,
                              void* d_out, int out_size, void* d_ws, size_t ws_size,
                              hipStream_t stream) {
    const int*   inputs = (const int*)d_in[0];     // (B, V) int32
    const int*   prod   = (const int*)d_in[1];     // (L, E, 2) int32
    const int*   sc     = (const int*)d_in[2];     // (L, N, F) int32
    const float* ip     = (const float*)d_in[3];   // (V, K, C) f32
    const float* sp     = (const float*)d_in[4];   // (L, N, F) f32
    const float* rp     = (const float*)d_in[5];   // (N,) f32
    float* out = (float*)d_out;                    // (B,) f32

    float* nm0 = (float*)d_ws;                     // N*B floats (8 MB)
    float* nm1 = nm0 + (size_t)N_ * B_;            // N*B floats (8 MB)
    float* lws = nm1 + (size_t)N_ * B_;            // L*N*F floats (1 MB)
    float* pm  = lws + (size_t)L_ * N_ * F_;       // RCHUNKS*B floats (64 KB)
    float* ps  = pm + (size_t)RCHUNKS * B_;        // RCHUNKS*B floats (64 KB)
    float* ls  = ps + (size_t)RCHUNKS * B_;        // N floats (16 KB)

    norm_sum_kernel<<<(L_ * N_ + 255) / 256, 256, 0, stream>>>(sp, lws);
    row_ls_kernel<<<N_ / 4, 256, 0, stream>>>(ip, ls);
    input_kernel<<<8 * (N_ / 4), 256, 0, stream>>>(ip, inputs, ls, nm0);

    float* bufs[2] = {nm0, nm1};
    for (int l = 0; l < L_; l++)
        layer_kernel<<<8 * (N_ / 4), 256, 0, stream>>>(bufs[l & 1], bufs[(l + 1) & 1],
                                                       prod, sc, lws, l);
    // after L=4 layers the live buffer is bufs[0] = nm0
    root_partial_kernel<<<RCHUNKS * 8, 256, 0, stream>>>(bufs[L_ & 1], rp, pm, ps);
    root_merge_kernel<<<B_ / 256, 256, 0, stream>>>(pm, ps, rp, out);
}

// Round 5
// 150.534 us; speedup vs baseline: 3.1864x; 1.0257x over previous
//
#include <hip/hip_runtime.h>
#include <hip/hip_fp16.h>
#include <math.h>

#define V_ 128
#define K_ 32
#define C_ 256
#define L_ 4
#define N_ 4096
#define F_ 16
#define E_ 8192
#define B_ 512
#define EPS_ 1e-6f

#define RCHUNKS 64              // n-chunks for root phase A
#define CHUNK_N (N_ / RCHUNKS)  // 64

// ---------------------------------------------------------------------------
// Kernel 1: normalize sum_params in log domain (fp32).
// lw_sum[l,n,f] = log(sp+EPS) - log(sum_f(sp+EPS)).  One thread per (l,n) row.
// ---------------------------------------------------------------------------
__global__ __launch_bounds__(256) void norm_sum_kernel(const float* __restrict__ sp,
                                                       float* __restrict__ lws) {
    int idx = blockIdx.x * 256 + threadIdx.x;   // (l,n) row id, L*N = 16384
    if (idx >= L_ * N_) return;
    const float* row = sp + (size_t)idx * F_;
    float v[F_];
    float s = 0.f;
#pragma unroll
    for (int f = 0; f < F_; f++) { v[f] = row[f] + EPS_; s += v[f]; }
    float ls = __logf(s);
#pragma unroll
    for (int f = 0; f < F_; f++) lws[(size_t)idx * F_ + f] = __logf(v[f]) - ls;
}

// ---------------------------------------------------------------------------
// Kernel 2a: per-row input normalizer.  ls[n] = log(sum_c(ip[n,:]+EPS)).
// One wave per row; grid = N/4 blocks x 256 threads.
// ---------------------------------------------------------------------------
__global__ __launch_bounds__(256) void row_ls_kernel(const float* __restrict__ ip,
                                                     float* __restrict__ ls) {
    int n    = blockIdx.x * 4 + (threadIdx.x >> 6);
    int lane = threadIdx.x & 63;
    const float* row = ip + (size_t)n * C_;
    float t = 0.f;
#pragma unroll
    for (int i = 0; i < 4; i++) t += row[lane + 64 * i] + EPS_;
#pragma unroll
    for (int off = 32; off; off >>= 1) t += __shfl_down(t, off, 64);
    if (lane == 0) ls[n] = __logf(t);
}

// ---------------------------------------------------------------------------
// Kernel 2b: input layer gather -> fp16 nm0.
// Wave w handles n = ng*4+w; lane covers b = bg*128 + 2*lane (+1) via half2.
// Grid = 4 * (N/4) blocks, 256 threads.
// ---------------------------------------------------------------------------
__global__ __launch_bounds__(256) void input_kernel(const float* __restrict__ ip,
                                                    const int* __restrict__ inputs,
                                                    const float* __restrict__ ls,
                                                    __half* __restrict__ nm0) {
    int blk  = blockIdx.x;
    int bg   = blk & 3;              // 128-wide b-slice
    int ng   = blk >> 2;
    int w    = threadIdx.x >> 6;
    int lane = threadIdx.x & 63;
    int n    = ng * 4 + w;
    int v    = n >> 5;               // K = 32
    int b0   = bg * 128 + 2 * lane;
    int x0   = inputs[b0 * V_ + v];
    int x1   = inputs[(b0 + 1) * V_ + v];
    float lsn = ls[n];
    const float* row = ip + (size_t)n * C_;
    float r0 = __logf(row[x0] + EPS_) - lsn;
    float r1 = __logf(row[x1] + EPS_) - lsn;
    ((__half2*)(nm0 + (size_t)n * B_))[bg * 64 + lane] = __floats2half2_rn(r0, r1);
}

// ---------------------------------------------------------------------------
// Kernel 3: one circuit layer, em fused, fp16 storage, half2 gathers.
// nm_out[n,b] = logsumexp_f( nm_in[c0,b] + nm_in[c1,b] + lw_sum[l,n,f] )
// bg = blk&3 selects a 128-wide b-slice; blk%8 round-robins XCDs so each XCD
// touches only slice (xcd%4): 1 MB in + 1 MB out, L2-resident.
// Grid = 4 * (N/4) = 4096 blocks, 256 threads (4 waves = 4 n's, same slice).
// ---------------------------------------------------------------------------
__global__ __launch_bounds__(256) void layer_kernel(const __half* __restrict__ nm_in,
                                                    __half* __restrict__ nm_out,
                                                    const int* __restrict__ prod,
                                                    const int* __restrict__ sc,
                                                    const float* __restrict__ lws,
                                                    int l) {
    int blk  = blockIdx.x;
    int bg   = blk & 3;           // b-slice (low bits -> XCD round-robin)
    int ng   = blk >> 2;          // n-group of 4
    int tid  = threadIdx.x;
    int w    = tid >> 6;
    int lane = tid & 63;
    int n    = ng * 4 + w;
    int hb   = bg * 64 + lane;    // half2 index within a row

    __shared__ int   s_c0[4][F_];
    __shared__ int   s_c1[4][F_];
    __shared__ float s_lw[4][F_];
    if (tid < 64) {
        int w2 = tid >> 4, f = tid & 15;
        int n2 = ng * 4 + w2;
        int e  = sc[((size_t)l * N_ + n2) * F_ + f];
        s_c0[w2][f] = prod[((size_t)l * E_ + e) * 2 + 0];
        s_c1[w2][f] = prod[((size_t)l * E_ + e) * 2 + 1];
        s_lw[w2][f] = lws[((size_t)l * N_ + n2) * F_ + f];
    }
    __syncthreads();

    float2 a[F_];
#pragma unroll
    for (int f = 0; f < F_; f++) {
        const __half2* r0 = (const __half2*)(nm_in + (size_t)s_c0[w][f] * B_);
        const __half2* r1 = (const __half2*)(nm_in + (size_t)s_c1[w][f] * B_);
        float2 x0 = __half22float2(r0[hb]);
        float2 x1 = __half22float2(r1[hb]);
        float  wt = s_lw[w][f];
        a[f].x = x0.x + x1.x + wt;
        a[f].y = x0.y + x1.y + wt;
    }
    float mx = a[0].x, my = a[0].y;
#pragma unroll
    for (int f = 1; f < F_; f++) { mx = fmaxf(mx, a[f].x); my = fmaxf(my, a[f].y); }
    float sx = 0.f, sy = 0.f;
#pragma unroll
    for (int f = 0; f < F_; f++) { sx += __expf(a[f].x - mx); sy += __expf(a[f].y - my); }
    ((__half2*)(nm_out + (size_t)n * B_))[hb] =
        __floats2half2_rn(mx + __logf(sx), my + __logf(sy));
}

// ---------------------------------------------------------------------------
// Kernel 4a: root phase A — partial logsumexp over an n-chunk.
// Grid = RCHUNKS x 4 b-slices = 256 blocks (bg in LOW bits, same slicing).
// Two independent online-LSE streams per lane to break the serial chain.
// ---------------------------------------------------------------------------
__global__ __launch_bounds__(256) void root_partial_kernel(const __half* __restrict__ nm,
                                                           const float* __restrict__ rp,
                                                           float* __restrict__ pm,
                                                           float* __restrict__ ps) {
    int bg    = blockIdx.x & 3;           // b-slice
    int chunk = blockIdx.x >> 2;          // 0..RCHUNKS-1
    int tid   = threadIdx.x;
    int lane  = tid & 63;
    int w     = tid >> 6;                 // 0..3
    int hb    = bg * 64 + lane;
    int n0    = chunk * CHUNK_N;

    float2 mA = {-INFINITY, -INFINITY}, sA = {0.f, 0.f};
    float2 mB = {-INFINITY, -INFINITY}, sB = {0.f, 0.f};
    for (int i = w; i < CHUNK_N; i += 8) {
        // stream A: i, stream B: i+4
        {
            int    n  = n0 + i;
            float2 x  = __half22float2(((const __half2*)(nm + (size_t)n * B_))[hb]);
            float  lr = __logf(rp[n] + EPS_);
            float ax = x.x + lr, ay = x.y + lr;
            float Mx = fmaxf(mA.x, ax), My = fmaxf(mA.y, ay);
            sA.x = sA.x * __expf(mA.x - Mx) + __expf(ax - Mx);
            sA.y = sA.y * __expf(mA.y - My) + __expf(ay - My);
            mA.x = Mx; mA.y = My;
        }
        {
            int    n  = n0 + i + 4;
            float2 x  = __half22float2(((const __half2*)(nm + (size_t)n * B_))[hb]);
            float  lr = __logf(rp[n] + EPS_);
            float ax = x.x + lr, ay = x.y + lr;
            float Mx = fmaxf(mB.x, ax), My = fmaxf(mB.y, ay);
            sB.x = sB.x * __expf(mB.x - Mx) + __expf(ax - Mx);
            sB.y = sB.y * __expf(mB.y - My) + __expf(ay - My);
            mB.x = Mx; mB.y = My;
        }
    }
    // merge streams
    float2 m, s;
    {
        float Mx = fmaxf(mA.x, mB.x), My = fmaxf(mA.y, mB.y);
        s.x = sA.x * __expf(mA.x - Mx) + sB.x * __expf(mB.x - Mx);
        s.y = sA.y * __expf(mA.y - My) + sB.y * __expf(mB.y - My);
        m.x = Mx; m.y = My;
    }

    // merge the 4 wave partials within the block
    __shared__ float2 sm[4][64];
    __shared__ float2 ss[4][64];
    sm[w][lane] = m;
    ss[w][lane] = s;
    __syncthreads();
    if (w == 0) {
        float2 M = sm[0][lane], S = ss[0][lane];
#pragma unroll
        for (int i = 1; i < 4; i++) {
            float2 m2 = sm[i][lane], s2 = ss[i][lane];
            float Mx = fmaxf(M.x, m2.x), My = fmaxf(M.y, m2.y);
            S.x = S.x * __expf(M.x - Mx) + s2.x * __expf(m2.x - Mx);
            S.y = S.y * __expf(M.y - My) + s2.y * __expf(m2.y - My);
            M.x = Mx; M.y = My;
        }
        ((float2*)pm)[chunk * (B_ / 2) + hb] = M;   // pm[chunk*B + 2*hb 	(+1)]
        ((float2*)ps)[chunk * (B_ / 2) + hb] = S;
    }
}

// ---------------------------------------------------------------------------
// Kernel 4b: root phase B — merge RCHUNKS partials per b, subtract lroot.
// ---------------------------------------------------------------------------
__global__ __launch_bounds__(256) void root_merge_kernel(const float* __restrict__ pm,
                                                         const float* __restrict__ ps,
                                                         const float* __restrict__ rp,
                                                         float* __restrict__ out) {
    int tid = threadIdx.x;
    int b   = blockIdx.x * 256 + tid;

    __shared__ float smem[4];
    float acc = 0.f;
    for (int i = tid; i < N_; i += 256) acc += rp[i] + EPS_;
#pragma unroll
    for (int off = 32; off; off >>= 1) acc += __shfl_down(acc, off, 64);
    if ((tid & 63) == 0) smem[tid >> 6] = acc;
    __syncthreads();
    float lroot = __logf(smem[0] + smem[1] + smem[2] + smem[3]);

    float M = -INFINITY, S = 0.f;
#pragma unroll 8
    for (int c = 0; c < RCHUNKS; c++) {
        float m2 = pm[c * B_ + b], s2 = ps[c * B_ + b];
        float Mn = fmaxf(M, m2);
        S = S * __expf(M - Mn) + s2 * __expf(m2 - Mn);
        M = Mn;
    }
    out[b] = M + __logf(S) - lroot;
}

extern "C" void kernel_launch(void* const* d_in, const int* in_sizes, int n_in,
                              void* d_out, int out_size, void* d_ws, size_t ws_size,
                              hipStream_t stream) {
    const int*   inputs = (const int*)d_in[0];     // (B, V) int32
    const int*   prod   = (const int*)d_in[1];     // (L, E, 2) int32
    const int*   sc     = (const int*)d_in[2];     // (L, N, F) int32
    const float* ip     = (const float*)d_in[3];   // (V, K, C) f32
    const float* sp     = (const float*)d_in[4];   // (L, N, F) f32
    const float* rp     = (const float*)d_in[5];   // (N,) f32
    float* out = (float*)d_out;                    // (B,) f32

    float*  lws  = (float*)d_ws;                   // L*N*F floats (1 MB)
    float*  pm   = lws + (size_t)L_ * N_ * F_;     // RCHUNKS*B floats (128 KB)
    float*  ps   = pm + (size_t)RCHUNKS * B_;      // RCHUNKS*B floats (128 KB)
    float*  ls   = ps + (size_t)RCHUNKS * B_;      // N floats (16 KB)
    __half* nm0h = (__half*)(ls + N_);             // N*B halves (4 MB)
    __half* nm1h = nm0h + (size_t)N_ * B_;         // N*B halves (4 MB)

    norm_sum_kernel<<<(L_ * N_ + 255) / 256, 256, 0, stream>>>(sp, lws);
    row_ls_kernel<<<N_ / 4, 256, 0, stream>>>(ip, ls);
    input_kernel<<<4 * (N_ / 4), 256, 0, stream>>>(ip, inputs, ls, nm0h);

    __half* bufs[2] = {nm0h, nm1h};
    for (int l = 0; l < L_; l++)
        layer_kernel<<<4 * (N_ / 4), 256, 0, stream>>>(bufs[l & 1], bufs[(l + 1) & 1],
                                                       prod, sc, lws, l);
    // after L=4 layers the live buffer is bufs[0] = nm0h
    root_partial_kernel<<<RCHUNKS * 4, 256, 0, stream>>>(bufs[L_ & 1], rp, pm, ps);
    root_merge_kernel<<<B_ / 256, 256, 0, stream>>>(pm, ps, rp, out);
}

// Round 6
// 143.085 us; speedup vs baseline: 3.3523x; 1.0521x over previous
//
#include <hip/hip_runtime.h>
#include <hip/hip_fp16.h>
#include <math.h>

#define V_ 128
#define K_ 32
#define C_ 256
#define L_ 4
#define N_ 4096
#define F_ 16
#define E_ 8192
#define B_ 512
#define EPS_ 1e-6f

#define RCHUNKS 64              // n-chunks for root phase A
#define CHUNK_N (N_ / RCHUNKS)  // 64

// ---------------------------------------------------------------------------
// Kernel 1: normalize sum_params in log domain (fp32).
// lw_sum[l,n,f] = log(sp+EPS) - log(sum_f(sp+EPS)).  One thread per (l,n) row.
// ---------------------------------------------------------------------------
__global__ __launch_bounds__(256) void norm_sum_kernel(const float* __restrict__ sp,
                                                       float* __restrict__ lws) {
    int idx = blockIdx.x * 256 + threadIdx.x;   // (l,n) row id, L*N = 16384
    if (idx >= L_ * N_) return;
    const float* row = sp + (size_t)idx * F_;
    float v[F_];
    float s = 0.f;
#pragma unroll
    for (int f = 0; f < F_; f++) { v[f] = row[f] + EPS_; s += v[f]; }
    float ls = __logf(s);
#pragma unroll
    for (int f = 0; f < F_; f++) lws[(size_t)idx * F_ + f] = __logf(v[f]) - ls;
}

// ---------------------------------------------------------------------------
// Kernel 2a: per-row input normalizer.  ls[n] = log(sum_c(ip[n,:]+EPS)).
// One wave per row; grid = N/4 blocks x 256 threads.
// ---------------------------------------------------------------------------
__global__ __launch_bounds__(256) void row_ls_kernel(const float* __restrict__ ip,
                                                     float* __restrict__ ls) {
    int n    = blockIdx.x * 4 + (threadIdx.x >> 6);
    int lane = threadIdx.x & 63;
    const float* row = ip + (size_t)n * C_;
    float t = 0.f;
#pragma unroll
    for (int i = 0; i < 4; i++) t += row[lane + 64 * i] + EPS_;
#pragma unroll
    for (int off = 32; off; off >>= 1) t += __shfl_down(t, off, 64);
    if (lane == 0) ls[n] = __logf(t);
}

// ---------------------------------------------------------------------------
// Kernel 2b: input layer gather -> fp16 nm0, 8-way (64-b) XCD slicing.
// bg = blk&7 selects the 64-wide b-slice (low bits -> XCD round-robin).
// Block covers 8 n x 64 b: wave w = 2 n's, half-wave = 32 lanes x half2.
// Grid = 8 * (N/8) = 4096 blocks.
// ---------------------------------------------------------------------------
__global__ __launch_bounds__(256) void input_kernel(const float* __restrict__ ip,
                                                    const int* __restrict__ inputs,
                                                    const float* __restrict__ ls,
                                                    __half* __restrict__ nm0) {
    int blk  = blockIdx.x;
    int bg   = blk & 7;              // 64-wide b-slice / XCD
    int ng   = blk >> 3;             // 0..511
    int tid  = threadIdx.x;
    int w    = tid >> 6;
    int lane = tid & 63;
    int hs   = lane >> 5;            // which n of the wave's pair
    int hl   = lane & 31;            // half2 lane within the 64-b slice
    int n    = ng * 8 + 2 * w + hs;
    int v    = n >> 5;               // K = 32
    int b0   = bg * 64 + 2 * hl;
    int x0   = inputs[b0 * V_ + v];
    int x1   = inputs[(b0 + 1) * V_ + v];
    float lsn = ls[n];
    const float* row = ip + (size_t)n * C_;
    float r0 = __logf(row[x0] + EPS_) - lsn;
    float r1 = __logf(row[x1] + EPS_) - lsn;
    ((__half2*)(nm0 + (size_t)n * B_))[bg * 32 + hl] = __floats2half2_rn(r0, r1);
}

// ---------------------------------------------------------------------------
// Kernel 3: one circuit layer, em fused, fp16, strict 8-way XCD b-slicing.
// nm_out[n,b] = logsumexp_f( nm_in[c0,b] + nm_in[c1,b] + lw_sum[l,n,f] )
// Each XCD owns one 64-b slice: 512 KB in + 512 KB out, L2-resident; every
// row-slice is exactly one 128 B L2 line; each gather instr = 2 rows x 128 B.
// Grid = 8 * (N/8) = 4096 blocks, 256 threads (4 waves x 2 n = 8 n/block).
// ---------------------------------------------------------------------------
__global__ __launch_bounds__(256) void layer_kernel(const __half* __restrict__ nm_in,
                                                    __half* __restrict__ nm_out,
                                                    const int* __restrict__ prod,
                                                    const int* __restrict__ sc,
                                                    const float* __restrict__ lws,
                                                    int l) {
    int blk  = blockIdx.x;
    int bg   = blk & 7;           // b-slice / XCD (low bits -> round-robin)
    int ng   = blk >> 3;          // n-group of 8
    int tid  = threadIdx.x;
    int w    = tid >> 6;
    int lane = tid & 63;
    int hs   = lane >> 5;
    int hl   = lane & 31;
    int nw   = 2 * w + hs;        // 0..7: which n within the block
    int n    = ng * 8 + nw;
    int hb   = bg * 32 + hl;      // half2 col index within a row

    __shared__ int   s_c0[8][F_];
    __shared__ int   s_c1[8][F_];
    __shared__ float s_lw[8][F_];
    if (tid < 128) {
        int w2 = tid >> 4, f = tid & 15;
        int n2 = ng * 8 + w2;
        int e  = sc[((size_t)l * N_ + n2) * F_ + f];
        s_c0[w2][f] = prod[((size_t)l * E_ + e) * 2 + 0];
        s_c1[w2][f] = prod[((size_t)l * E_ + e) * 2 + 1];
        s_lw[w2][f] = lws[((size_t)l * N_ + n2) * F_ + f];
    }
    __syncthreads();

    float2 a[F_];
#pragma unroll
    for (int f = 0; f < F_; f++) {
        const __half2* r0 = (const __half2*)(nm_in + (size_t)s_c0[nw][f] * B_);
        const __half2* r1 = (const __half2*)(nm_in + (size_t)s_c1[nw][f] * B_);
        float2 x0 = __half22float2(r0[hb]);
        float2 x1 = __half22float2(r1[hb]);
        float  wt = s_lw[nw][f];
        a[f].x = x0.x + x1.x + wt;
        a[f].y = x0.y + x1.y + wt;
    }
    float mx = a[0].x, my = a[0].y;
#pragma unroll
    for (int f = 1; f < F_; f++) { mx = fmaxf(mx, a[f].x); my = fmaxf(my, a[f].y); }
    float sx = 0.f, sy = 0.f;
#pragma unroll
    for (int f = 0; f < F_; f++) { sx += __expf(a[f].x - mx); sy += __expf(a[f].y - my); }
    ((__half2*)(nm_out + (size_t)n * B_))[hb] =
        __floats2half2_rn(mx + __logf(sx), my + __logf(sy));
}

// ---------------------------------------------------------------------------
// Kernel 4a: root phase A — partial logsumexp over an n-chunk.
// Grid = RCHUNKS x 8 b-slices (bg in LOW bits, same 64-b slicing as layers).
// Lane owns one b (half loads, 128 B per row-gather); 2 LSE streams/lane.
// ---------------------------------------------------------------------------
__global__ __launch_bounds__(256) void root_partial_kernel(const __half* __restrict__ nm,
                                                           const float* __restrict__ rp,
                                                           float* __restrict__ pm,
                                                           float* __restrict__ ps) {
    int bg    = blockIdx.x & 7;           // b-slice / XCD
    int chunk = blockIdx.x >> 3;          // 0..RCHUNKS-1
    int tid   = threadIdx.x;
    int lane  = tid & 63;
    int w     = tid >> 6;                 // 0..3
    int b     = bg * 64 + lane;
    int n0    = chunk * CHUNK_N;

    float mA = -INFINITY, sA = 0.f;
    float mB = -INFINITY, sB = 0.f;
    for (int i = w; i < CHUNK_N; i += 8) {
        {
            int   n  = n0 + i;
            float x  = __half2float(nm[(size_t)n * B_ + b]);
            float a  = x + __logf(rp[n] + EPS_);
            float Mn = fmaxf(mA, a);
            sA = sA * __expf(mA - Mn) + __expf(a - Mn);
            mA = Mn;
        }
        {
            int   n  = n0 + i + 4;
            float x  = __half2float(nm[(size_t)n * B_ + b]);
            float a  = x + __logf(rp[n] + EPS_);
            float Mn = fmaxf(mB, a);
            sB = sB * __expf(mB - Mn) + __expf(a - Mn);
            mB = Mn;
        }
    }
    float m, s;
    {
        float Mn = fmaxf(mA, mB);
        s = sA * __expf(mA - Mn) + sB * __expf(mB - Mn);
        m = Mn;
    }

    __shared__ float sm[4][64];
    __shared__ float ss[4][64];
    sm[w][lane] = m;
    ss[w][lane] = s;
    __syncthreads();
    if (w == 0) {
        float M = sm[0][lane], S = ss[0][lane];
#pragma unroll
        for (int i = 1; i < 4; i++) {
            float m2 = sm[i][lane], s2 = ss[i][lane];
            float Mn = fmaxf(M, m2);
            S = S * __expf(M - Mn) + s2 * __expf(m2 - Mn);
            M = Mn;
        }
        pm[chunk * B_ + b] = M;
        ps[chunk * B_ + b] = S;
    }
}

// ---------------------------------------------------------------------------
// Kernel 4b: root phase B — merge RCHUNKS partials per b, subtract lroot.
// ---------------------------------------------------------------------------
__global__ __launch_bounds__(256) void root_merge_kernel(const float* __restrict__ pm,
                                                         const float* __restrict__ ps,
                                                         const float* __restrict__ rp,
                                                         float* __restrict__ out) {
    int tid = threadIdx.x;
    int b   = blockIdx.x * 256 + tid;

    __shared__ float smem[4];
    float acc = 0.f;
    for (int i = tid; i < N_; i += 256) acc += rp[i] + EPS_;
#pragma unroll
    for (int off = 32; off; off >>= 1) acc += __shfl_down(acc, off, 64);
    if ((tid & 63) == 0) smem[tid >> 6] = acc;
    __syncthreads();
    float lroot = __logf(smem[0] + smem[1] + smem[2] + smem[3]);

    float M = -INFINITY, S = 0.f;
#pragma unroll 8
    for (int c = 0; c < RCHUNKS; c++) {
        float m2 = pm[c * B_ + b], s2 = ps[c * B_ + b];
        float Mn = fmaxf(M, m2);
        S = S * __expf(M - Mn) + s2 * __expf(m2 - Mn);
        M = Mn;
    }
    out[b] = M + __logf(S) - lroot;
}

extern "C" void kernel_launch(void* const* d_in, const int* in_sizes, int n_in,
                              void* d_out, int out_size, void* d_ws, size_t ws_size,
                              hipStream_t stream) {
    const int*   inputs = (const int*)d_in[0];     // (B, V) int32
    const int*   prod   = (const int*)d_in[1];     // (L, E, 2) int32
    const int*   sc     = (const int*)d_in[2];     // (L, N, F) int32
    const float* ip     = (const float*)d_in[3];   // (V, K, C) f32
    const float* sp     = (const float*)d_in[4];   // (L, N, F) f32
    const float* rp     = (const float*)d_in[5];   // (N,) f32
    float* out = (float*)d_out;                    // (B,) f32

    float*  lws  = (float*)d_ws;                   // L*N*F floats (1 MB)
    float*  pm   = lws + (size_t)L_ * N_ * F_;     // RCHUNKS*B floats (128 KB)
    float*  ps   = pm + (size_t)RCHUNKS * B_;      // RCHUNKS*B floats (128 KB)
    float*  ls   = ps + (size_t)RCHUNKS * B_;      // N floats (16 KB)
    __half* nm0h = (__half*)(ls + N_);             // N*B halves (4 MB)
    __half* nm1h = nm0h + (size_t)N_ * B_;         // N*B halves (4 MB)

    norm_sum_kernel<<<(L_ * N_ + 255) / 256, 256, 0, stream>>>(sp, lws);
    row_ls_kernel<<<N_ / 4, 256, 0, stream>>>(ip, ls);
    input_kernel<<<N_, 256, 0, stream>>>(ip, inputs, ls, nm0h);   // 8*(N/8)=N blocks

    __half* bufs[2] = {nm0h, nm1h};
    for (int l = 0; l < L_; l++)
        layer_kernel<<<N_, 256, 0, stream>>>(bufs[l & 1], bufs[(l + 1) & 1],
                                             prod, sc, lws, l);
    // after L=4 layers the live buffer is bufs[0] = nm0h
    root_partial_kernel<<<RCHUNKS * 8, 256, 0, stream>>>(bufs[L_ & 1], rp, pm, ps);
    root_merge_kernel<<<B_ / 256, 256, 0, stream>>>(pm, ps, rp, out);
}